// Round 1
// baseline (649.872 us; speedup 1.0000x reference)
//
#include <hip/hip_runtime.h>

// LoRA attention: B=4, S=2048, E=1024, R=16, fp32 in/out.
// Strategy: bf16 MFMA (16x16x32) for all 6 GEMMs, fp32 accumulate.
//   Q = q@Wq^T + (q@QA^T)@QB^T   (LoRA folded as extra zero-padded K-step)
//   K likewise; V computed TRANSPOSED as VT = Wv@v^T (+ LoRA swapped) so the
//   PV GEMM can use the same fast B^T-layout kernel.
//   scores = Q@K^T /32 -> bf16, softmax in place, out = P@V, final = out@Wo^T.
// Workspace: ~105 MB (scores alias qb+kb staging; attn aliases vb).

#define S_LEN 2048
#define E_DIM 1024

typedef __attribute__((ext_vector_type(8))) short short8;
typedef __attribute__((ext_vector_type(4))) float floatx4;

__device__ __forceinline__ unsigned short f2bf(float f) {
  union { float f; unsigned int u; } x; x.f = f;
  return (unsigned short)((x.u + 0x7fffu + ((x.u >> 16) & 1u)) >> 16);  // RNE
}
__device__ __forceinline__ float bf2f(unsigned short h) {
  union { unsigned int u; float f; } x; x.u = ((unsigned int)h) << 16;
  return x.f;
}

// async global->LDS, 16B per lane; LDS dest must be wave-uniform base (+lane*16)
__device__ __forceinline__ void gld_lds16(const unsigned short* g, unsigned short* l) {
  __builtin_amdgcn_global_load_lds(
      (const __attribute__((address_space(1))) unsigned int*)(const void*)g,
      (__attribute__((address_space(3))) unsigned int*)(void*)l,
      16, 0, 0);
}

// C[m][n] = scale * (sum_k A[m][k]*B[n][k]  (+ LoRA: sum_r LA[m][r]*LB[n][r]))
// A: [M][lda] bf16, B: [N][ldb] bf16 (B^T layout), C: [M][ldc] f32 or bf16.
// Grid: (N/128, M/128, batches). All dims assumed multiples of 128/32.
template<bool LORA, bool OUTF32>
__global__ __launch_bounds__(256) void gemm_bt(
    const unsigned short* __restrict__ A, const unsigned short* __restrict__ B,
    void* __restrict__ Cv,
    const unsigned short* __restrict__ LA, const unsigned short* __restrict__ LB,
    long lda, long ldb, long ldc, int K, float scale,
    long batA, long batB, long batC) {
  __shared__ alignas(16) unsigned short As[4096];  // 128 rows x 32 bf16
  __shared__ alignas(16) unsigned short Bs[4096];

  const int tid  = threadIdx.x;
  const int wave = tid >> 6, lane = tid & 63;
  const int quad = lane >> 4, l16 = lane & 15;
  const int wr = wave >> 1, wc = wave & 1;  // 2x2 waves, each 64x64
  const long m0 = (long)blockIdx.y * 128;
  const long n0 = (long)blockIdx.x * 128;
  A += (long)blockIdx.z * batA;
  B += (long)blockIdx.z * batB;

  floatx4 acc[4][4];
#pragma unroll
  for (int i = 0; i < 4; ++i)
#pragma unroll
    for (int j = 0; j < 4; ++j) acc[i][j] = (floatx4){0.f, 0.f, 0.f, 0.f};

  // staging: chunk c = it*256 + tid; row = c>>2, k-offset = (c&3)*8 elems
  const long srow  = tid >> 2;
  const int  skoff = (tid & 3) * 8;
  const unsigned short* a_base = A + (m0 + srow) * lda + skoff;
  const unsigned short* b_base = B + (n0 + srow) * ldb + skoff;
  unsigned short* as0 = &As[wave * 512];
  unsigned short* as1 = &As[2048 + wave * 512];
  unsigned short* bs0 = &Bs[wave * 512];
  unsigned short* bs1 = &Bs[2048 + wave * 512];

  for (int k0 = 0; k0 < K; k0 += 32) {
    gld_lds16(a_base + k0, as0);
    gld_lds16(a_base + 64 * lda + k0, as1);
    gld_lds16(b_base + k0, bs0);
    gld_lds16(b_base + 64 * ldb + k0, bs1);
    __syncthreads();
    short8 afrag[4], bfrag[4];
#pragma unroll
    for (int i = 0; i < 4; ++i)
      afrag[i] = *(const short8*)&As[(wr * 64 + i * 16 + l16) * 32 + quad * 8];
#pragma unroll
    for (int j = 0; j < 4; ++j)
      bfrag[j] = *(const short8*)&Bs[(wc * 64 + j * 16 + l16) * 32 + quad * 8];
#pragma unroll
    for (int i = 0; i < 4; ++i)
#pragma unroll
      for (int j = 0; j < 4; ++j)
        acc[i][j] = __builtin_amdgcn_mfma_f32_16x16x32_bf16(afrag[i], bfrag[j], acc[i][j], 0, 0, 0);
    __syncthreads();
  }

  if constexpr (LORA) {
    // one extra K-step: As rows <- LA[m0+r][0..16) zero-padded to 32, Bs <- LB
    const int r = tid >> 1, h = tid & 1;
    uint4* arow = (uint4*)&As[r * 32 + h * 16];
    uint4* brow = (uint4*)&Bs[r * 32 + h * 16];
    if (h == 0) {
      const uint4* sa = (const uint4*)(LA + (m0 + r) * 16);
      arow[0] = sa[0]; arow[1] = sa[1];
      const uint4* sb = (const uint4*)(LB + (n0 + r) * 16);
      brow[0] = sb[0]; brow[1] = sb[1];
    } else {
      uint4 z; z.x = z.y = z.z = z.w = 0u;
      arow[0] = z; arow[1] = z;
      brow[0] = z; brow[1] = z;
    }
    __syncthreads();
    short8 afrag[4], bfrag[4];
#pragma unroll
    for (int i = 0; i < 4; ++i)
      afrag[i] = *(const short8*)&As[(wr * 64 + i * 16 + l16) * 32 + quad * 8];
#pragma unroll
    for (int j = 0; j < 4; ++j)
      bfrag[j] = *(const short8*)&Bs[(wc * 64 + j * 16 + l16) * 32 + quad * 8];
#pragma unroll
    for (int i = 0; i < 4; ++i)
#pragma unroll
      for (int j = 0; j < 4; ++j)
        acc[i][j] = __builtin_amdgcn_mfma_f32_16x16x32_bf16(afrag[i], bfrag[j], acc[i][j], 0, 0, 0);
  }

  // epilogue: C/D layout col=lane&15, row=quad*4+rr  [verified mapping]
#pragma unroll
  for (int i = 0; i < 4; ++i) {
    const long row = m0 + wr * 64 + i * 16 + quad * 4;
#pragma unroll
    for (int j = 0; j < 4; ++j) {
      const long col = n0 + wc * 64 + j * 16 + l16;
#pragma unroll
      for (int rr = 0; rr < 4; ++rr) {
        float val = acc[i][j][rr] * scale;
        if constexpr (OUTF32)
          ((float*)Cv)[(long)blockIdx.z * batC + (row + rr) * ldc + col] = val;
        else
          ((unsigned short*)Cv)[(long)blockIdx.z * batC + (row + rr) * ldc + col] = f2bf(val);
      }
    }
  }
}

// fp32 -> bf16, 8 elems/thread; n must be a multiple of 2048
__global__ __launch_bounds__(256) void cvt_bf16(const float* __restrict__ x,
                                                unsigned short* __restrict__ y, int n) {
  int i = (blockIdx.x * 256 + threadIdx.x) * 8;
  if (i >= n) return;
  float4 a = *(const float4*)(x + i);
  float4 b = *(const float4*)(x + i + 4);
  uint4 o;
  o.x = (unsigned int)f2bf(a.x) | ((unsigned int)f2bf(a.y) << 16);
  o.y = (unsigned int)f2bf(a.z) | ((unsigned int)f2bf(a.w) << 16);
  o.z = (unsigned int)f2bf(b.x) | ((unsigned int)f2bf(b.y) << 16);
  o.w = (unsigned int)f2bf(b.z) | ((unsigned int)f2bf(b.w) << 16);
  *(uint4*)(y + i) = o;
}

// T[m][r] = sum_k X[m][k] * Am[r][k]   (X: [8192][1024] f32, Am: [16][1024] f32)
__global__ __launch_bounds__(256) void lora_T_kernel(const float* __restrict__ X,
                                                     const float* __restrict__ Am,
                                                     unsigned short* __restrict__ T) {
  const int tid = threadIdx.x;
  const long m = (long)blockIdx.x * 16 + (tid >> 4);
  const int r = tid & 15;
  const float* xr = X + m * 1024;
  const float* ar = Am + (long)r * 1024;
  float s = 0.f;
#pragma unroll 4
  for (int k = 0; k < 1024; k += 4) {
    float4 xv = *(const float4*)(xr + k);
    float4 av = *(const float4*)(ar + k);
    s += xv.x * av.x + xv.y * av.y + xv.z * av.z + xv.w * av.w;
  }
  T[m * 16 + r] = f2bf(s);
}

// in-place row softmax over 2048 bf16 scores; one block per row
__global__ __launch_bounds__(256) void softmax_kernel(unsigned short* __restrict__ S) {
  const long base = (long)blockIdx.x * 2048;
  const int tid = threadIdx.x;
  const int lane = tid & 63, wave = tid >> 6;
  __shared__ float redm[4], reds[4];
  uint4 raw = *(const uint4*)(S + base + tid * 8);
  unsigned int w[4] = {raw.x, raw.y, raw.z, raw.w};
  float v[8];
#pragma unroll
  for (int i = 0; i < 4; ++i) {
    v[2 * i]     = bf2f((unsigned short)(w[i] & 0xffffu));
    v[2 * i + 1] = bf2f((unsigned short)(w[i] >> 16));
  }
  float m = v[0];
#pragma unroll
  for (int i = 1; i < 8; ++i) m = fmaxf(m, v[i]);
  for (int off = 32; off >= 1; off >>= 1) m = fmaxf(m, __shfl_xor(m, off, 64));
  if (lane == 0) redm[wave] = m;
  __syncthreads();
  m = fmaxf(fmaxf(redm[0], redm[1]), fmaxf(redm[2], redm[3]));
  float e[8], s = 0.f;
#pragma unroll
  for (int i = 0; i < 8; ++i) { e[i] = __expf(v[i] - m); s += e[i]; }
  for (int off = 32; off >= 1; off >>= 1) s += __shfl_xor(s, off, 64);
  if (lane == 0) reds[wave] = s;
  __syncthreads();
  s = reds[0] + reds[1] + reds[2] + reds[3];
  const float inv = 1.0f / s;
  uint4 o;
  o.x = (unsigned int)f2bf(e[0] * inv) | ((unsigned int)f2bf(e[1] * inv) << 16);
  o.y = (unsigned int)f2bf(e[2] * inv) | ((unsigned int)f2bf(e[3] * inv) << 16);
  o.z = (unsigned int)f2bf(e[4] * inv) | ((unsigned int)f2bf(e[5] * inv) << 16);
  o.w = (unsigned int)f2bf(e[6] * inv) | ((unsigned int)f2bf(e[7] * inv) << 16);
  *(uint4*)(S + base + tid * 8) = o;
}

extern "C" void kernel_launch(void* const* d_in, const int* in_sizes, int n_in,
                              void* d_out, int out_size, void* d_ws, size_t ws_size,
                              hipStream_t stream) {
  const float* q  = (const float*)d_in[0];
  const float* k  = (const float*)d_in[1];
  const float* v  = (const float*)d_in[2];
  const float* Wq = (const float*)d_in[3];
  const float* Wk = (const float*)d_in[4];
  const float* Wv = (const float*)d_in[5];
  const float* QA = (const float*)d_in[6];
  const float* QB = (const float*)d_in[7];
  const float* KA = (const float*)d_in[8];
  const float* KB = (const float*)d_in[9];
  const float* VA = (const float*)d_in[10];
  const float* VB = (const float*)d_in[11];
  const float* Wo = (const float*)d_in[12];

  // workspace layout (bf16 elems); total ~105 MB
  unsigned short* W = (unsigned short*)d_ws;
  const long SEe = (long)8192 * 1024;  // 8388608
  unsigned short* qb  = W;             // dead after Q-proj -> scores low half
  unsigned short* kb  = W + SEe;       // dead after K-proj -> scores high half
  unsigned short* vb  = W + 2 * SEe;   // dead after V-proj -> attn buffer
  unsigned short* Qp  = W + 3 * SEe;
  unsigned short* Kp  = W + 4 * SEe;
  unsigned short* VT  = W + 5 * SEe;   // [1024][8192] = V^T, col = b*2048+s
  unsigned short* wqb = W + 6 * SEe;
  unsigned short* wkb = wqb + 1048576;
  unsigned short* wvb = wkb + 1048576;
  unsigned short* wob = wvb + 1048576;
  unsigned short* Bqb = wob + 1048576;
  unsigned short* Bkb = Bqb + 16384;
  unsigned short* Bvb = Bkb + 16384;
  unsigned short* Tq  = Bvb + 16384;   // [8192][16]
  unsigned short* Tk  = Tq + 131072;
  unsigned short* Tv  = Tk + 131072;
  unsigned short* scores = W;          // [4][2048][2048] bf16, aliases qb+kb
  unsigned short* attn   = vb;         // [8192][1024] bf16, aliases vb

  dim3 blk(256, 1, 1);
  // fp32 -> bf16 staging
  cvt_bf16<<<4096, blk, 0, stream>>>(q, qb, 8388608);
  cvt_bf16<<<4096, blk, 0, stream>>>(k, kb, 8388608);
  cvt_bf16<<<4096, blk, 0, stream>>>(v, vb, 8388608);
  cvt_bf16<<<512, blk, 0, stream>>>(Wq, wqb, 1048576);
  cvt_bf16<<<512, blk, 0, stream>>>(Wk, wkb, 1048576);
  cvt_bf16<<<512, blk, 0, stream>>>(Wv, wvb, 1048576);
  cvt_bf16<<<512, blk, 0, stream>>>(Wo, wob, 1048576);
  cvt_bf16<<<8, blk, 0, stream>>>(QB, Bqb, 16384);
  cvt_bf16<<<8, blk, 0, stream>>>(KB, Bkb, 16384);
  cvt_bf16<<<8, blk, 0, stream>>>(VB, Bvb, 16384);
  // LoRA T = X @ A^T (fp32 inputs for accuracy)
  lora_T_kernel<<<512, blk, 0, stream>>>(q, QA, Tq);
  lora_T_kernel<<<512, blk, 0, stream>>>(k, KA, Tk);
  lora_T_kernel<<<512, blk, 0, stream>>>(v, VA, Tv);

  // Q = qb@Wq^T + Tq@Bq^T   (M=8192,N=1024,K=1024)
  gemm_bt<true, false><<<dim3(8, 64, 1), blk, 0, stream>>>(
      qb, wqb, Qp, Tq, Bqb, 1024, 1024, 1024, 1024, 1.0f, 0, 0, 0);
  gemm_bt<true, false><<<dim3(8, 64, 1), blk, 0, stream>>>(
      kb, wkb, Kp, Tk, Bkb, 1024, 1024, 1024, 1024, 1.0f, 0, 0, 0);
  // VT = Wv@vb^T + Bv@Tv^T  (M=1024,N=8192, C row-stride 8192)
  gemm_bt<true, false><<<dim3(64, 8, 1), blk, 0, stream>>>(
      wvb, vb, VT, Bvb, Tv, 1024, 1024, 8192, 1024, 1.0f, 0, 0, 0);
  // scores = Qp@Kp^T / 32   (batched, M=N=2048,K=1024)
  gemm_bt<false, false><<<dim3(16, 16, 4), blk, 0, stream>>>(
      Qp, Kp, scores, nullptr, nullptr, 1024, 1024, 2048, 1024, 0.03125f,
      (long)S_LEN * E_DIM, (long)S_LEN * E_DIM, (long)S_LEN * S_LEN);
  softmax_kernel<<<8192, blk, 0, stream>>>(scores);
  // attn_out = P@V = P@(VT)^T  (batched, M=2048,N=1024,K=2048; VT batch = col offset)
  gemm_bt<false, false><<<dim3(8, 16, 4), blk, 0, stream>>>(
      scores, VT, attn, nullptr, nullptr, 2048, 8192, 1024, 2048, 1.0f,
      (long)S_LEN * S_LEN, (long)S_LEN, (long)S_LEN * E_DIM);
  // final = attn@Wo^T -> fp32 d_out  (M=8192,N=1024,K=1024)
  gemm_bt<false, true><<<dim3(8, 64, 1), blk, 0, stream>>>(
      attn, wob, d_out, nullptr, nullptr, 1024, 1024, 1024, 1024, 1.0f, 0, 0, 0);
}